// Round 1
// baseline (714.770 us; speedup 1.0000x reference)
//
#include <hip/hip_runtime.h>
#include <hip/hip_bf16.h>
#include <stdint.h>

typedef float  f32x16 __attribute__((ext_vector_type(16)));
typedef __bf16 bf16x8 __attribute__((ext_vector_type(8)));

#define NH 1280
#define KBLKS 80                       // 1280 / 16
#define MAT_ELEMS (KBLKS * NH * 16)    // 1,638,400 u16 elems per 1280x1280 matrix

// workspace offsets (bytes)
#define OFF_W1S  0u          // 2 halves * 3,276,800 B
#define OFF_W2S  6553600u
#define OFF_W3S  9830400u
#define OFF_HI   13107200u   // 1024*1280 f32
#define OFF_HJB  18350080u   // 1024*1280 f32 (hj + b1)
// total: 23,592,960 B

__device__ __forceinline__ unsigned short bfb(float f) {
    unsigned u = __builtin_bit_cast(unsigned, f);
    u += 0x7fffu + ((u >> 16) & 1u);          // RNE
    return (unsigned short)(u >> 16);
}
__device__ __forceinline__ unsigned pk2(float lo, float hi) {
    return (unsigned)bfb(lo) | ((unsigned)bfb(hi) << 16);
}
// LDS tile: 64 rows x 1280 bf16, row stride 2560B, XOR swizzle on byte bits 4-6
__device__ __forceinline__ unsigned swz(unsigned row, unsigned kb) {
    return row * 2560u + (kb ^ ((row & 7u) << 4));
}

// ---------------------------------------------------------------------------
// Convert a 1280x1280 f32 row-major (k-major) matrix into bf16 MFMA-B
// fragment-linear layout: elem e = (kblk*1280 + col)*16 + half*8 + j
// holds src[(kblk*16 + half*8 + j)*1280 + col].
// A wave's B-frag load (col = base + (lane&31), k0 + (lane>>5)*8 .. +7) is
// then one fully-contiguous 2KB global_load_dwordx4.
// ---------------------------------------------------------------------------
__global__ void k_cvt(const float* __restrict__ src, unsigned short* __restrict__ dst) {
    int e = blockIdx.x * 256 + threadIdx.x;
    if (e >= MAT_ELEMS) return;
    int j = e & 7, hv = (e >> 3) & 1;
    int t = e >> 4;
    int col = t % NH, kblk = t / NH;
    int k = kblk * 16 + hv * 8 + j;
    dst[e] = bfb(src[(size_t)k * NH + col]);
}

// ---------------------------------------------------------------------------
// Shared GEMM inner loop: C(64x160 per wave) += A(LDS 64x1280 bf16, swizzled)
//                                             @ B(frag-linear global bf16)
// acc[rf][cf]: rf in {0,1} row-blocks of 32, cf in {0..4} col-blocks of 32.
// ---------------------------------------------------------------------------
__device__ __forceinline__ void gemm80(const char* lds, const unsigned short* __restrict__ Bf,
                                       int colbase, int lane, f32x16 acc[2][5]) {
    const int rlo = lane & 31, hsel = lane >> 5;
    const unsigned xr = ((unsigned)(rlo & 7)) << 4;
    const char* a0p = lds + (unsigned)rlo * 2560u;
    const char* a1p = lds + (unsigned)(rlo + 32) * 2560u;
    const char* bp  = (const char*)Bf + ((size_t)(colbase + rlo) * 16 + (size_t)hsel * 8) * 2;
    for (int kblk = 0; kblk < KBLKS; ++kblk) {
        unsigned ko = ((unsigned)kblk * 32u + (unsigned)hsel * 16u) ^ xr;
        bf16x8 a0 = __builtin_bit_cast(bf16x8, *(const uint4*)(a0p + ko));
        bf16x8 a1 = __builtin_bit_cast(bf16x8, *(const uint4*)(a1p + ko));
        bf16x8 bb[5];
#pragma unroll
        for (int cf = 0; cf < 5; ++cf)
            bb[cf] = __builtin_bit_cast(bf16x8, *(const uint4*)(bp + (size_t)(kblk * NH + cf * 32) * 32));
#pragma unroll
        for (int cf = 0; cf < 5; ++cf) {
            acc[0][cf] = __builtin_amdgcn_mfma_f32_32x32x16_bf16(a0, bb[cf], acc[0][cf], 0, 0, 0);
            acc[1][cf] = __builtin_amdgcn_mfma_f32_32x32x16_bf16(a1, bb[cf], acc[1][cf], 0, 0, 0);
        }
    }
}

__device__ __forceinline__ void zero_acc(f32x16 acc[2][5]) {
#pragma unroll
    for (int rf = 0; rf < 2; ++rf)
#pragma unroll
        for (int cf = 0; cf < 5; ++cf)
#pragma unroll
            for (int i = 0; i < 16; ++i) acc[rf][cf][i] = 0.f;
}

// ---------------------------------------------------------------------------
// Hi[b,m,:] = roi[b,m,:] @ W1[:C]  ;  Hjb[b,n,:] = roi[b,n,:] @ W1[C:] + b1
// One WG per (b, half). A-tile = roi[b] as bf16 in LDS.
// ---------------------------------------------------------------------------
__global__ __launch_bounds__(512, 2) void k_hihj(const float* __restrict__ roi, const float* __restrict__ b1,
                                                 const unsigned short* __restrict__ w1s,
                                                 float* __restrict__ Hi, float* __restrict__ Hjb) {
    __shared__ __align__(16) char lds[163840];
    const int b = blockIdx.x >> 1, hh = blockIdx.x & 1;
    const int tid = threadIdx.x;
    const float* src = roi + (size_t)b * 64 * NH;
    for (int idx = tid; idx < 64 * 160; idx += 512) {
        int row = idx / 160, kc = idx - row * 160;
        int k = kc * 8;
        const float4 v0 = *(const float4*)(src + row * NH + k);
        const float4 v1 = *(const float4*)(src + row * NH + k + 4);
        uint4 pk;
        pk.x = pk2(v0.x, v0.y); pk.y = pk2(v0.z, v0.w);
        pk.z = pk2(v1.x, v1.y); pk.w = pk2(v1.z, v1.w);
        *(uint4*)(lds + swz(row, (unsigned)k * 2u)) = pk;
    }
    __syncthreads();
    const int wave = tid >> 6, lane = tid & 63;
    const int colbase = wave * 160, rlo = lane & 31;
    f32x16 acc[2][5];
    zero_acc(acc);
    gemm80(lds, w1s + (size_t)hh * MAT_ELEMS, colbase, lane, acc);
    float bias[5];
#pragma unroll
    for (int cf = 0; cf < 5; ++cf) bias[cf] = hh ? b1[colbase + cf * 32 + rlo] : 0.f;
    float* dst = hh ? Hjb : Hi;
#pragma unroll
    for (int rf = 0; rf < 2; ++rf)
#pragma unroll
        for (int cf = 0; cf < 5; ++cf) {
            int col = colbase + cf * 32 + rlo;
#pragma unroll
            for (int j = 0; j < 16; ++j) {
                int row = rf * 32 + (j & 3) + ((j >> 2) << 3) + ((lane >> 5) << 2);
                dst[(size_t)(b * 64 + row) * NH + col] = acc[rf][cf][j] + bias[cf];
            }
        }
}

// ---------------------------------------------------------------------------
// Main fused kernel. One WG per (b, n): rows m = 0..63.
// Phase A: h1 = relu(Hi[b,m,:] + Hjb[b,n,:]) -> LDS bf16 (swizzled)
// GEMM1:   h2acc = h1 @ W2                   (B-frags direct from L2)
// Phase C: h2 = relu(h2acc + b2) -> bf16 -> same LDS buffer
// GEMM2:   h3acc = h2 @ W3
// Phase E: out[b,col] += sum_rows relu(h3acc + b3)   (atomicAdd)
// ---------------------------------------------------------------------------
__global__ __launch_bounds__(512, 2) void k_main(const float* __restrict__ Hi, const float* __restrict__ Hjb,
                                                 const float* __restrict__ b2, const float* __restrict__ b3,
                                                 const unsigned short* __restrict__ w2s,
                                                 const unsigned short* __restrict__ w3s,
                                                 float* __restrict__ out) {
    __shared__ __align__(16) char lds[163840];
    const int b = blockIdx.x >> 6, n = blockIdx.x & 63;
    const int tid = threadIdx.x;
    const float* HiB = Hi + (size_t)b * 64 * NH;
    const float* Hj  = Hjb + (size_t)(b * 64 + n) * NH;
    for (int idx = tid; idx < 64 * 160; idx += 512) {
        int row = idx / 160, kc = idx - row * 160;
        int k = kc * 8;
        const float4 v0 = *(const float4*)(HiB + row * NH + k);
        const float4 v1 = *(const float4*)(HiB + row * NH + k + 4);
        const float4 j0 = *(const float4*)(Hj + k);
        const float4 j1 = *(const float4*)(Hj + k + 4);
        uint4 pk;
        pk.x = pk2(fmaxf(v0.x + j0.x, 0.f), fmaxf(v0.y + j0.y, 0.f));
        pk.y = pk2(fmaxf(v0.z + j0.z, 0.f), fmaxf(v0.w + j0.w, 0.f));
        pk.z = pk2(fmaxf(v1.x + j1.x, 0.f), fmaxf(v1.y + j1.y, 0.f));
        pk.w = pk2(fmaxf(v1.z + j1.z, 0.f), fmaxf(v1.w + j1.w, 0.f));
        *(uint4*)(lds + swz(row, (unsigned)k * 2u)) = pk;
    }
    __syncthreads();
    const int wave = tid >> 6, lane = tid & 63;
    const int colbase = wave * 160, rlo = lane & 31, hsel = lane >> 5;

    f32x16 acc[2][5];
    zero_acc(acc);
    gemm80(lds, w2s, colbase, lane, acc);
    __syncthreads();                 // all waves done reading h1

    float b2v[5];
#pragma unroll
    for (int cf = 0; cf < 5; ++cf) b2v[cf] = b2[colbase + cf * 32 + rlo];
#pragma unroll
    for (int rf = 0; rf < 2; ++rf)
#pragma unroll
        for (int cf = 0; cf < 5; ++cf) {
            int col = colbase + cf * 32 + rlo;
#pragma unroll
            for (int j = 0; j < 16; ++j) {
                int row = rf * 32 + (j & 3) + ((j >> 2) << 3) + (hsel << 2);
                float v = fmaxf(acc[rf][cf][j] + b2v[cf], 0.f);
                *(unsigned short*)(lds + swz(row, (unsigned)col * 2u)) = bfb(v);
            }
        }
    __syncthreads();                 // h2 tile complete

    zero_acc(acc);
    gemm80(lds, w3s, colbase, lane, acc);

    float b3v[5];
#pragma unroll
    for (int cf = 0; cf < 5; ++cf) b3v[cf] = b3[colbase + cf * 32 + rlo];
#pragma unroll
    for (int cf = 0; cf < 5; ++cf) {
        float s = 0.f;
#pragma unroll
        for (int rf = 0; rf < 2; ++rf)
#pragma unroll
            for (int j = 0; j < 16; ++j) s += fmaxf(acc[rf][cf][j] + b3v[cf], 0.f);
        s += __shfl_xor(s, 32);      // other 32 rows live on lane ^ 32
        if (lane < 32) atomicAdd(out + b * NH + colbase + cf * 32 + lane, s);
    }
}

extern "C" void kernel_launch(void* const* d_in, const int* in_sizes, int n_in,
                              void* d_out, int out_size, void* d_ws, size_t ws_size,
                              hipStream_t stream) {
    const float* roi = (const float*)d_in[0];
    const float* W1  = (const float*)d_in[1];
    const float* b1  = (const float*)d_in[2];
    const float* W2  = (const float*)d_in[3];
    const float* b2  = (const float*)d_in[4];
    const float* W3  = (const float*)d_in[5];
    const float* b3  = (const float*)d_in[6];
    float* out = (float*)d_out;
    char* ws = (char*)d_ws;
    unsigned short* w1s = (unsigned short*)(ws + OFF_W1S);
    unsigned short* w2s = (unsigned short*)(ws + OFF_W2S);
    unsigned short* w3s = (unsigned short*)(ws + OFF_W3S);
    float* Hi  = (float*)(ws + OFF_HI);
    float* Hjb = (float*)(ws + OFF_HJB);

    hipMemsetAsync(out, 0, (size_t)16 * NH * sizeof(float), stream);

    const int cvtBlocks = MAT_ELEMS / 256;                       // 6400
    k_cvt<<<cvtBlocks, 256, 0, stream>>>(W1, w1s);               // W1 rows [0,1280)
    k_cvt<<<cvtBlocks, 256, 0, stream>>>(W1 + (size_t)NH * NH, w1s + MAT_ELEMS); // rows [1280,2560)
    k_cvt<<<cvtBlocks, 256, 0, stream>>>(W2, w2s);
    k_cvt<<<cvtBlocks, 256, 0, stream>>>(W3, w3s);

    k_hihj<<<32, 512, 0, stream>>>(roi, b1, w1s, Hi, Hjb);
    k_main<<<16 * 64, 512, 0, stream>>>(Hi, Hjb, b2, b3, w2s, w3s, out);
}

// Round 2
// 530.359 us; speedup vs baseline: 1.3477x; 1.3477x over previous
//
#include <hip/hip_runtime.h>
#include <hip/hip_bf16.h>
#include <stdint.h>

typedef float  f32x16 __attribute__((ext_vector_type(16)));
typedef __bf16 bf16x8 __attribute__((ext_vector_type(8)));
typedef unsigned u32x4 __attribute__((ext_vector_type(4)));

#define NH 1280
#define KBLKS 80                       // 1280 / 16
#define MAT_ELEMS (KBLKS * NH * 16)    // 1,638,400 u16 elems per 1280x1280 matrix

// workspace offsets (bytes)
#define OFF_W1S  0u          // 2 halves * 3,276,800 B
#define OFF_W2S  6553600u
#define OFF_W3S  9830400u
#define OFF_HI   13107200u   // 1024*1280 f32
#define OFF_HJB  18350080u   // 1024*1280 f32 (hj + b1)
#define OFF_H2   23592960u   // 1024 tiles * 163840 B  (bf16 LDS-image of h2)
#define WS_SPLIT (23592960ull + 1024ull * 163840ull)   // 191,365,120

__device__ __forceinline__ unsigned short bfb(float f) {
    unsigned u = __builtin_bit_cast(unsigned, f);
    u += 0x7fffu + ((u >> 16) & 1u);          // RNE
    return (unsigned short)(u >> 16);
}
__device__ __forceinline__ unsigned pk2(float lo, float hi) {
    return (unsigned)bfb(lo) | ((unsigned)bfb(hi) << 16);
}
// LDS tile: 64 rows x 1280 bf16, row stride 2560B, XOR swizzle on byte bits 4-6
__device__ __forceinline__ unsigned swz(unsigned row, unsigned kb) {
    return row * 2560u + (kb ^ ((row & 7u) << 4));
}

// ---------------------------------------------------------------------------
// Convert 1280x1280 f32 row-major (k-major) -> bf16 MFMA-B fragment-linear:
// elem e = (kblk*1280 + col)*16 + r  holds  src[(kblk*16 + r)*1280 + col].
// Tiled through LDS: coalesced reads (16 rows x 256 cols) and 32B/thread
// coalesced writes. Grid dim3(80, 5), block 256.
// ---------------------------------------------------------------------------
__global__ void k_cvt(const float* __restrict__ src, unsigned short* __restrict__ dst) {
    __shared__ float tile[16][257];
    const int kb = blockIdx.x, cb = blockIdx.y, t = threadIdx.x;
#pragma unroll
    for (int r = 0; r < 16; ++r)
        tile[r][t] = src[(size_t)(kb * 16 + r) * NH + cb * 256 + t];
    __syncthreads();
    const int col = cb * 256 + t;
    unsigned u[8];
#pragma unroll
    for (int i = 0; i < 8; ++i) u[i] = pk2(tile[2 * i][t], tile[2 * i + 1][t]);
    u32x4* d = (u32x4*)(dst + ((size_t)kb * NH + col) * 16);
    u32x4 w0 = {u[0], u[1], u[2], u[3]}, w1 = {u[4], u[5], u[6], u[7]};
    d[0] = w0; d[1] = w1;
}

// ---------------------------------------------------------------------------
// GEMM inner loop: C(64x160 per wave) += A(LDS 64x1280 bf16, swizzled)
//                                      @ B(frag-linear global bf16)
// 2-deep register double-buffer on the B fragments so L2 latency hides
// under the other buffer's MFMAs.
// ---------------------------------------------------------------------------
__device__ __forceinline__ void gemm80(const char* lds, const unsigned short* __restrict__ Bf,
                                       int colbase, int lane, f32x16 acc[2][5]) {
    const int rlo = lane & 31, hsel = lane >> 5;
    const unsigned xr = ((unsigned)(rlo & 7)) << 4;
    const char* a0p = lds + (unsigned)rlo * 2560u;
    const char* a1p = lds + (unsigned)(rlo + 32) * 2560u;
    const char* bp  = (const char*)Bf + ((size_t)(colbase + rlo) * 16 + (size_t)hsel * 8) * 2;

#define LDB(dst_, kb_) do { _Pragma("unroll") \
    for (int cf = 0; cf < 5; ++cf) \
        dst_[cf] = __builtin_bit_cast(bf16x8, *(const uint4*)(bp + (size_t)(kb_) * (NH * 32) + cf * 1024)); \
    } while (0)
#define MFMA5(a0_, a1_, bb_) do { _Pragma("unroll") \
    for (int cf = 0; cf < 5; ++cf) { \
        acc[0][cf] = __builtin_amdgcn_mfma_f32_32x32x16_bf16(a0_, bb_[cf], acc[0][cf], 0, 0, 0); \
        acc[1][cf] = __builtin_amdgcn_mfma_f32_32x32x16_bf16(a1_, bb_[cf], acc[1][cf], 0, 0, 0); \
    } } while (0)

    bf16x8 bA[5], bB[5];
    LDB(bA, 0); LDB(bB, 1);
    for (int kblk = 0; kblk < KBLKS - 2; kblk += 2) {
        unsigned ko0 = (((unsigned)kblk) * 32u + (unsigned)hsel * 16u) ^ xr;
        unsigned ko1 = (((unsigned)kblk + 1u) * 32u + (unsigned)hsel * 16u) ^ xr;
        bf16x8 a00 = __builtin_bit_cast(bf16x8, *(const uint4*)(a0p + ko0));
        bf16x8 a01 = __builtin_bit_cast(bf16x8, *(const uint4*)(a1p + ko0));
        bf16x8 a10 = __builtin_bit_cast(bf16x8, *(const uint4*)(a0p + ko1));
        bf16x8 a11 = __builtin_bit_cast(bf16x8, *(const uint4*)(a1p + ko1));
        MFMA5(a00, a01, bA);
        LDB(bA, kblk + 2);
        MFMA5(a10, a11, bB);
        LDB(bB, kblk + 3);
    }
    {   // tail: kblk = 78, 79
        unsigned ko0 = (78u * 32u + (unsigned)hsel * 16u) ^ xr;
        unsigned ko1 = (79u * 32u + (unsigned)hsel * 16u) ^ xr;
        bf16x8 a00 = __builtin_bit_cast(bf16x8, *(const uint4*)(a0p + ko0));
        bf16x8 a01 = __builtin_bit_cast(bf16x8, *(const uint4*)(a1p + ko0));
        bf16x8 a10 = __builtin_bit_cast(bf16x8, *(const uint4*)(a0p + ko1));
        bf16x8 a11 = __builtin_bit_cast(bf16x8, *(const uint4*)(a1p + ko1));
        MFMA5(a00, a01, bA);
        MFMA5(a10, a11, bB);
    }
#undef LDB
#undef MFMA5
}

__device__ __forceinline__ void zero_acc(f32x16 acc[2][5]) {
#pragma unroll
    for (int rf = 0; rf < 2; ++rf)
#pragma unroll
        for (int cf = 0; cf < 5; ++cf)
#pragma unroll
            for (int i = 0; i < 16; ++i) acc[rf][cf][i] = 0.f;
}

// ---------------------------------------------------------------------------
// Hi[b,m,:] = roi[b,m,:] @ W1[:C]  ;  Hjb[b,n,:] = roi[b,n,:] @ W1[C:] + b1
// ---------------------------------------------------------------------------
__global__ __launch_bounds__(512, 2) void k_hihj(const float* __restrict__ roi, const float* __restrict__ b1,
                                                 const unsigned short* __restrict__ w1s,
                                                 float* __restrict__ Hi, float* __restrict__ Hjb) {
    __shared__ __align__(16) char lds[163840];
    const int b = blockIdx.x >> 1, hh = blockIdx.x & 1;
    const int tid = threadIdx.x;
    const float* src = roi + (size_t)b * 64 * NH;
    for (int idx = tid; idx < 64 * 160; idx += 512) {
        int row = idx / 160, kc = idx - row * 160;
        int k = kc * 8;
        const float4 v0 = *(const float4*)(src + row * NH + k);
        const float4 v1 = *(const float4*)(src + row * NH + k + 4);
        uint4 pk;
        pk.x = pk2(v0.x, v0.y); pk.y = pk2(v0.z, v0.w);
        pk.z = pk2(v1.x, v1.y); pk.w = pk2(v1.z, v1.w);
        *(uint4*)(lds + swz(row, (unsigned)k * 2u)) = pk;
    }
    __syncthreads();
    const int wave = tid >> 6, lane = tid & 63;
    const int colbase = wave * 160, rlo = lane & 31;
    f32x16 acc[2][5];
    zero_acc(acc);
    gemm80(lds, w1s + (size_t)hh * MAT_ELEMS, colbase, lane, acc);
    float bias[5];
#pragma unroll
    for (int cf = 0; cf < 5; ++cf) bias[cf] = hh ? b1[colbase + cf * 32 + rlo] : 0.f;
    float* dst = hh ? Hjb : Hi;
#pragma unroll
    for (int rf = 0; rf < 2; ++rf)
#pragma unroll
        for (int cf = 0; cf < 5; ++cf) {
            int col = colbase + cf * 32 + rlo;
#pragma unroll
            for (int j = 0; j < 16; ++j) {
                int row = rf * 32 + (j & 3) + ((j >> 2) << 3) + ((lane >> 5) << 2);
                dst[(size_t)(b * 64 + row) * NH + col] = acc[rf][cf][j] + bias[cf];
            }
        }
}

// ---------------------------------------------------------------------------
// k_g1: per (b,n): h1 = relu(Hi + Hj) -> LDS; h2 = relu(h1@W2 + b2) -> LDS
// image -> coalesced NT store to ws. Only W2 hot -> L2-resident.
// ---------------------------------------------------------------------------
__global__ __launch_bounds__(512, 2) void k_g1(const float* __restrict__ Hi, const float* __restrict__ Hjb,
                                               const float* __restrict__ b2,
                                               const unsigned short* __restrict__ w2s,
                                               char* __restrict__ h2g) {
    __shared__ __align__(16) char lds[163840];
    const int bn = blockIdx.x, b = bn >> 6, n = bn & 63;
    const int tid = threadIdx.x;
    const float* HiB = Hi + (size_t)b * 64 * NH;
    const float* Hj  = Hjb + (size_t)(b * 64 + n) * NH;
    for (int idx = tid; idx < 64 * 160; idx += 512) {
        int row = idx / 160, kc = idx - row * 160;
        int k = kc * 8;
        const float4 v0 = *(const float4*)(HiB + row * NH + k);
        const float4 v1 = *(const float4*)(HiB + row * NH + k + 4);
        const float4 j0 = *(const float4*)(Hj + k);
        const float4 j1 = *(const float4*)(Hj + k + 4);
        uint4 pk;
        pk.x = pk2(fmaxf(v0.x + j0.x, 0.f), fmaxf(v0.y + j0.y, 0.f));
        pk.y = pk2(fmaxf(v0.z + j0.z, 0.f), fmaxf(v0.w + j0.w, 0.f));
        pk.z = pk2(fmaxf(v1.x + j1.x, 0.f), fmaxf(v1.y + j1.y, 0.f));
        pk.w = pk2(fmaxf(v1.z + j1.z, 0.f), fmaxf(v1.w + j1.w, 0.f));
        *(uint4*)(lds + swz(row, (unsigned)k * 2u)) = pk;
    }
    __syncthreads();
    const int wave = tid >> 6, lane = tid & 63;
    const int colbase = wave * 160, rlo = lane & 31, hsel = lane >> 5;

    f32x16 acc[2][5];
    zero_acc(acc);
    gemm80(lds, w2s, colbase, lane, acc);
    __syncthreads();                 // all waves done reading h1

    float b2v[5];
#pragma unroll
    for (int cf = 0; cf < 5; ++cf) b2v[cf] = b2[colbase + cf * 32 + rlo];
#pragma unroll
    for (int rf = 0; rf < 2; ++rf)
#pragma unroll
        for (int cf = 0; cf < 5; ++cf) {
            int col = colbase + cf * 32 + rlo;
#pragma unroll
            for (int j = 0; j < 16; ++j) {
                int row = rf * 32 + (j & 3) + ((j >> 2) << 3) + (hsel << 2);
                float v = fmaxf(acc[rf][cf][j] + b2v[cf], 0.f);
                *(unsigned short*)(lds + swz(row, (unsigned)col * 2u)) = bfb(v);
            }
        }
    __syncthreads();                 // h2 image complete

    const u32x4* s = (const u32x4*)lds;
    u32x4* d = (u32x4*)(h2g + (size_t)bn * 163840);
    for (int idx = tid; idx < 10240; idx += 512)
        __builtin_nontemporal_store(s[idx], d + idx);
}

// ---------------------------------------------------------------------------
// k_g2: per (b,n): load h2 image -> LDS (NT), h3 = relu(h2@W3 + b3),
// row-reduce, atomicAdd into out. Only W3 hot -> L2-resident.
// ---------------------------------------------------------------------------
__global__ __launch_bounds__(512, 2) void k_g2(const char* __restrict__ h2g,
                                               const float* __restrict__ b3,
                                               const unsigned short* __restrict__ w3s,
                                               float* __restrict__ out) {
    __shared__ __align__(16) char lds[163840];
    const int bn = blockIdx.x, b = bn >> 6;
    const int tid = threadIdx.x;
    const u32x4* src = (const u32x4*)(h2g + (size_t)bn * 163840);
    for (int idx = tid; idx < 10240; idx += 512)
        *(u32x4*)(lds + (size_t)idx * 16) = __builtin_nontemporal_load(src + idx);
    __syncthreads();
    const int wave = tid >> 6, lane = tid & 63;
    const int colbase = wave * 160, rlo = lane & 31;

    f32x16 acc[2][5];
    zero_acc(acc);
    gemm80(lds, w3s, colbase, lane, acc);

    float b3v[5];
#pragma unroll
    for (int cf = 0; cf < 5; ++cf) b3v[cf] = b3[colbase + cf * 32 + rlo];
#pragma unroll
    for (int cf = 0; cf < 5; ++cf) {
        float s = 0.f;
#pragma unroll
        for (int rf = 0; rf < 2; ++rf)
#pragma unroll
            for (int j = 0; j < 16; ++j) s += fmaxf(acc[rf][cf][j] + b3v[cf], 0.f);
        s += __shfl_xor(s, 32);      // other 32 rows live on lane ^ 32
        if (lane < 32) atomicAdd(out + b * NH + colbase + cf * 32 + lane, s);
    }
}

// ---------------------------------------------------------------------------
// Fallback fused kernel (used only if ws is too small for the h2 buffer).
// ---------------------------------------------------------------------------
__global__ __launch_bounds__(512, 2) void k_main(const float* __restrict__ Hi, const float* __restrict__ Hjb,
                                                 const float* __restrict__ b2, const float* __restrict__ b3,
                                                 const unsigned short* __restrict__ w2s,
                                                 const unsigned short* __restrict__ w3s,
                                                 float* __restrict__ out) {
    __shared__ __align__(16) char lds[163840];
    const int b = blockIdx.x >> 6, n = blockIdx.x & 63;
    const int tid = threadIdx.x;
    const float* HiB = Hi + (size_t)b * 64 * NH;
    const float* Hj  = Hjb + (size_t)(b * 64 + n) * NH;
    for (int idx = tid; idx < 64 * 160; idx += 512) {
        int row = idx / 160, kc = idx - row * 160;
        int k = kc * 8;
        const float4 v0 = *(const float4*)(HiB + row * NH + k);
        const float4 v1 = *(const float4*)(HiB + row * NH + k + 4);
        const float4 j0 = *(const float4*)(Hj + k);
        const float4 j1 = *(const float4*)(Hj + k + 4);
        uint4 pk;
        pk.x = pk2(fmaxf(v0.x + j0.x, 0.f), fmaxf(v0.y + j0.y, 0.f));
        pk.y = pk2(fmaxf(v0.z + j0.z, 0.f), fmaxf(v0.w + j0.w, 0.f));
        pk.z = pk2(fmaxf(v1.x + j1.x, 0.f), fmaxf(v1.y + j1.y, 0.f));
        pk.w = pk2(fmaxf(v1.z + j1.z, 0.f), fmaxf(v1.w + j1.w, 0.f));
        *(uint4*)(lds + swz(row, (unsigned)k * 2u)) = pk;
    }
    __syncthreads();
    const int wave = tid >> 6, lane = tid & 63;
    const int colbase = wave * 160, rlo = lane & 31, hsel = lane >> 5;

    f32x16 acc[2][5];
    zero_acc(acc);
    gemm80(lds, w2s, colbase, lane, acc);
    __syncthreads();

    float b2v[5];
#pragma unroll
    for (int cf = 0; cf < 5; ++cf) b2v[cf] = b2[colbase + cf * 32 + rlo];
#pragma unroll
    for (int rf = 0; rf < 2; ++rf)
#pragma unroll
        for (int cf = 0; cf < 5; ++cf) {
            int col = colbase + cf * 32 + rlo;
#pragma unroll
            for (int j = 0; j < 16; ++j) {
                int row = rf * 32 + (j & 3) + ((j >> 2) << 3) + (hsel << 2);
                float v = fmaxf(acc[rf][cf][j] + b2v[cf], 0.f);
                *(unsigned short*)(lds + swz(row, (unsigned)col * 2u)) = bfb(v);
            }
        }
    __syncthreads();

    zero_acc(acc);
    gemm80(lds, w3s, colbase, lane, acc);

    float b3v[5];
#pragma unroll
    for (int cf = 0; cf < 5; ++cf) b3v[cf] = b3[colbase + cf * 32 + rlo];
#pragma unroll
    for (int cf = 0; cf < 5; ++cf) {
        float s = 0.f;
#pragma unroll
        for (int rf = 0; rf < 2; ++rf)
#pragma unroll
            for (int j = 0; j < 16; ++j) s += fmaxf(acc[rf][cf][j] + b3v[cf], 0.f);
        s += __shfl_xor(s, 32);
        if (lane < 32) atomicAdd(out + b * NH + colbase + cf * 32 + lane, s);
    }
}

extern "C" void kernel_launch(void* const* d_in, const int* in_sizes, int n_in,
                              void* d_out, int out_size, void* d_ws, size_t ws_size,
                              hipStream_t stream) {
    const float* roi = (const float*)d_in[0];
    const float* W1  = (const float*)d_in[1];
    const float* b1  = (const float*)d_in[2];
    const float* W2  = (const float*)d_in[3];
    const float* b2  = (const float*)d_in[4];
    const float* W3  = (const float*)d_in[5];
    const float* b3  = (const float*)d_in[6];
    float* out = (float*)d_out;
    char* ws = (char*)d_ws;
    unsigned short* w1s = (unsigned short*)(ws + OFF_W1S);
    unsigned short* w2s = (unsigned short*)(ws + OFF_W2S);
    unsigned short* w3s = (unsigned short*)(ws + OFF_W3S);
    float* Hi  = (float*)(ws + OFF_HI);
    float* Hjb = (float*)(ws + OFF_HJB);
    char*  h2g = ws + OFF_H2;

    hipMemsetAsync(out, 0, (size_t)16 * NH * sizeof(float), stream);

    k_cvt<<<dim3(80, 5), 256, 0, stream>>>(W1, w1s);                          // W1 rows [0,1280)
    k_cvt<<<dim3(80, 5), 256, 0, stream>>>(W1 + (size_t)NH * NH, w1s + MAT_ELEMS); // rows [1280,2560)
    k_cvt<<<dim3(80, 5), 256, 0, stream>>>(W2, w2s);
    k_cvt<<<dim3(80, 5), 256, 0, stream>>>(W3, w3s);

    k_hihj<<<32, 512, 0, stream>>>(roi, b1, w1s, Hi, Hjb);

    if (ws_size >= WS_SPLIT) {
        k_g1<<<16 * 64, 512, 0, stream>>>(Hi, Hjb, b2, w2s, h2g);
        k_g2<<<16 * 64, 512, 0, stream>>>(h2g, b3, w3s, out);
    } else {
        k_main<<<16 * 64, 512, 0, stream>>>(Hi, Hjb, b2, b3, w2s, w3s, out);
    }
}